// Round 10
// baseline (2229.150 us; speedup 1.0000x reference)
//
#include <hip/hip_runtime.h>

using u32 = unsigned int;
using u64 = unsigned long long;
using bf16x8 = __attribute__((ext_vector_type(8))) short;
using f32x4  = __attribute__((ext_vector_type(4))) float;

// Problem constants
#define BB_ 64
#define TT_ 512
#define II_ 1024
#define HH_ 1024
#define NSCAN_BLOCKS 128   // 4 domains (16 batch rows) x 32 j-blocks (32 cols)

__device__ __forceinline__ unsigned short bf16rne(float f) {
  u32 u = __float_as_uint(f);
  return (unsigned short)((u + 0x7FFFu + ((u >> 16) & 1u)) >> 16);
}
__device__ __forceinline__ u32 pk2(float a, float b) {
  u32 ua = __float_as_uint(a), ub = __float_as_uint(b);
  u32 lo = (ua + 0x7FFFu + ((ua >> 16) & 1u)) >> 16;
  u32 hi = (ub + 0x7FFFu + ((ub >> 16) & 1u)) & 0xFFFF0000u;
  return lo | hi;
}
__device__ __forceinline__ void gll16(const void* g, void* s) {
  __builtin_amdgcn_global_load_lds(
      (const __attribute__((address_space(1))) u32*)g,
      (__attribute__((address_space(3))) u32*)s, 16, 0, 0);
}
// fast tanh: 1 - 2/(exp2(2*log2e*x)+1); |err| < 1e-6, exact +-1 saturation
__device__ __forceinline__ float tanhfast(float x) {
  float e = __builtin_amdgcn_exp2f(x * 2.885390081777927f);
  return 1.0f - 2.0f / (e + 1.0f);
}

__device__ __forceinline__ void cvt4(const float* __restrict__ s, unsigned short* __restrict__ d, long long g) {
  float4 v = ((const float4*)s)[g];
  ushort4 o;
  o.x = bf16rne(v.x); o.y = bf16rne(v.y); o.z = bf16rne(v.z); o.w = bf16rne(v.w);
  ((ushort4*)d)[g] = o;
}

// ---------------------------------------------------------------------------
// k_convert (r1-proven): bf16 copies of x / W_ih / [W_hh1;W_hh2],
// hbuf[parity0]=bf16(h0), flags (16KB) = 0. Replay-safe (full rewrite).
// ---------------------------------------------------------------------------
__global__ void k_convert(const float* __restrict__ x, const float* __restrict__ h0,
                          const float* __restrict__ Wih, const float* __restrict__ Wh1,
                          const float* __restrict__ Wh2,
                          unsigned short* __restrict__ xb, unsigned short* __restrict__ Wihb,
                          unsigned short* __restrict__ Wcatb, unsigned short* __restrict__ hbuf,
                          int* __restrict__ cnt, int do_x) {
  const long long NWI = (long long)HH_ * II_ / 4;
  const long long NH0 = (long long)BB_ * HH_ / 4;
  const long long NC  = 1024;  // 4096 flag u32s via int4 (16 KB)
  const long long NX  = do_x ? ((long long)BB_ * TT_ * II_ / 4) : 0;
  const long long total = 3 * NWI + NH0 + NC + NX;
  for (long long g = (long long)blockIdx.x * blockDim.x + threadIdx.x; g < total;
       g += (long long)gridDim.x * blockDim.x) {
    if (g < NWI) {
      cvt4(Wih, Wihb, g);
    } else if (g < 2 * NWI) {
      cvt4(Wh1, Wcatb, g - NWI);
    } else if (g < 3 * NWI) {
      cvt4(Wh2, Wcatb + (long long)HH_ * II_, g - 2 * NWI);
    } else if (g < 3 * NWI + NH0) {
      cvt4(h0, hbuf, g - 3 * NWI);
    } else if (g < 3 * NWI + NH0 + NC) {
      ((int4*)cnt)[g - 3 * NWI - NH0] = make_int4(0, 0, 0, 0);
    } else {
      cvt4(x, xb, g - (3 * NWI + NH0 + NC));
    }
  }
}

// ---------------------------------------------------------------------------
// k_gemm: xp = x @ Wih^T + b_ih, written into d_out with NON-TEMPORAL stores
// (keeps the LLC clean for the scan's hot hbuf/flags). Otherwise unchanged.
// ---------------------------------------------------------------------------
template <bool XB>
__global__ __launch_bounds__(256) void k_gemm(const unsigned short* __restrict__ xbg,
                                              const float* __restrict__ xf,
                                              const unsigned short* __restrict__ Wb,
                                              const float* __restrict__ bias,
                                              float* __restrict__ C) {
  __shared__ __align__(16) unsigned short ldsA[128 * 64];
  __shared__ __align__(16) unsigned short ldsB[128 * 64];
  const int tid = threadIdx.x;
  const int w = tid >> 6, l = tid & 63;
  const int lr = l & 15, lk = l >> 4;
  const int n0 = (blockIdx.x & 7) * 128;
  const int m0 = (blockIdx.x >> 3) * 128;
  const int mbase = (w >> 1) * 64, nbase = (w & 1) * 64;

  f32x4 acc[4][4] = {};

  for (int kb = 0; kb < 16; ++kb) {
    const int k0 = kb * 64;
#pragma unroll
    for (int r = 0; r < 4; ++r) {
      int tb = r * 4096 + w * 1024 + l * 16;
      int row = tb >> 7;
      int p = (tb >> 4) & 7;
      int c = p ^ (row & 7);
      gll16(Wb + (u64)(n0 + row) * II_ + k0 + c * 8,
            (char*)ldsB + r * 4096 + w * 1024);
    }
    if constexpr (XB) {
#pragma unroll
      for (int r = 0; r < 4; ++r) {
        int tb = r * 4096 + w * 1024 + l * 16;
        int row = tb >> 7;
        int p = (tb >> 4) & 7;
        int c = p ^ (row & 7);
        gll16(xbg + (u64)(m0 + row) * II_ + k0 + c * 8,
              (char*)ldsA + r * 4096 + w * 1024);
      }
    } else {
      const int r = tid >> 1, ch = tid & 1;
      const float* gs = xf + (u64)(m0 + r) * II_ + k0 + ch * 32;
      float4 v[8];
#pragma unroll
      for (int q = 0; q < 8; ++q) v[q] = ((const float4*)gs)[q];
#pragma unroll
      for (int q = 0; q < 4; ++q) {
        int c = ch * 4 + q;
        int p = c ^ (r & 7);
        uint4 pk;
        pk.x = pk2(v[2 * q].x, v[2 * q].y);
        pk.y = pk2(v[2 * q].z, v[2 * q].w);
        pk.z = pk2(v[2 * q + 1].x, v[2 * q + 1].y);
        pk.w = pk2(v[2 * q + 1].z, v[2 * q + 1].w);
        *(uint4*)((char*)ldsA + r * 128 + p * 16) = pk;
      }
    }
    __syncthreads();

    bf16x8 a[4][2], b[4][2];
#pragma unroll
    for (int mt = 0; mt < 4; ++mt) {
      int row = mbase + mt * 16 + lr;
#pragma unroll
      for (int kk = 0; kk < 2; ++kk) {
        int c = kk * 4 + lk, p = c ^ (row & 7);
        a[mt][kk] = *(const bf16x8*)((const char*)ldsA + row * 128 + p * 16);
      }
    }
#pragma unroll
    for (int nt = 0; nt < 4; ++nt) {
      int row = nbase + nt * 16 + lr;
#pragma unroll
      for (int kk = 0; kk < 2; ++kk) {
        int c = kk * 4 + lk, p = c ^ (row & 7);
        b[nt][kk] = *(const bf16x8*)((const char*)ldsB + row * 128 + p * 16);
      }
    }
#pragma unroll
    for (int kk = 0; kk < 2; ++kk)
#pragma unroll
      for (int mt = 0; mt < 4; ++mt)
#pragma unroll
        for (int nt = 0; nt < 4; ++nt)
          acc[mt][nt] = __builtin_amdgcn_mfma_f32_16x16x32_bf16(a[mt][kk], b[nt][kk], acc[mt][nt], 0, 0, 0);
    __syncthreads();
  }

  float bn[4];
#pragma unroll
  for (int nt = 0; nt < 4; ++nt) bn[nt] = bias[n0 + nbase + nt * 16 + lr];
#pragma unroll
  for (int mt = 0; mt < 4; ++mt) {
#pragma unroll
    for (int i = 0; i < 4; ++i) {
      int m = m0 + mbase + mt * 16 + lk * 4 + i;
      float* cr = C + (u64)m * HH_ + n0 + nbase + lr;
#pragma unroll
      for (int nt = 0; nt < 4; ++nt)
        __builtin_nontemporal_store(acc[mt][nt][i] + bn[nt], cr + nt * 16);
    }
  }
}

// ---------------------------------------------------------------------------
// k_scan v10 = r9 (proven best, 2030us) + two surgical changes:
//  (1) PER-WAVE dependency poll: wave w consumes k-slice [w*256, w*256+256)
//      produced by exactly 8 blocks (og = w*8..w*8+7). Each wave polls only
//      those 8 flags (lane l&7; 64B-strided lines) and proceeds immediately
//      to its own h loads + MFMA -- no post-poll block barrier (the
//      pre-combine __syncthreads orders part[] writes; part[] WAR is covered
//      by the publish barrier of step t-1). Fan-in 32 -> 8.
//  (2) NON-TEMPORAL xp loads + out stores (plus nt xp-write in k_gemm):
//      the 134MB streams stop evicting the 272KB hot set (hbuf+flags) from
//      LLC, so polls and h-loads stay at LLC latency instead of HBM.
// Everything else verbatim from r9 (AGPR-pinned weights via asm MFMA,
// LDS K-combine stride-65, direct u32 h-store epilogue mapping, relaxed
// flag after vmcnt(0)+barrier, equality flags + double buffer).
// ---------------------------------------------------------------------------
__global__ __launch_bounds__(256, 1) void k_scan(float* __restrict__ out, const float* __restrict__ h0,
                                                 const float* __restrict__ b1, const float* __restrict__ b2,
                                                 const unsigned short* __restrict__ Wcat,
                                                 unsigned short* __restrict__ hbuf, u32* __restrict__ flags) {
  __shared__ float part[16 * 4 * 65];  // [(w*4+nt)*4+i][l] stride 65 = 16.6KB
  const int tid = threadIdx.x, w = tid >> 6, l = tid & 63;
  const int lr = l & 15, lk = l >> 4;
  const int og = blockIdx.x & 31, bg = blockIdx.x >> 5;
  const int jb = og * 32, bb = bg * 16;
  const int koff = w * 256;

  // --- weights -> 128 AGPRs: nt 0/1 = W_hh1 j-tiles, 2/3 = W_hh2 j-tiles ---
  bf16x8 wt[4][8];
#pragma unroll
  for (int nt = 0; nt < 4; ++nt) {
    int nrow = (nt < 2) ? (jb + nt * 16 + lr) : (HH_ + jb + (nt - 2) * 16 + lr);
    const unsigned short* wr = Wcat + (u64)nrow * HH_ + koff + lk * 8;
#pragma unroll
    for (int kk = 0; kk < 8; ++kk) wt[nt][kk] = *(const bf16x8*)(wr + kk * 32);
  }

  // --- epilogue identity: batch row b = tid&15, col pair jp = tid>>4 ---
  const int b = tid & 15, jp = tid >> 4;
  const int grow = bb + b;
  const int c0 = jb + jp * 2;          // global col of q=0
  float bv1[2] = {b1[c0], b1[c0 + 1]};
  float bv2[2] = {b2[c0], b2[c0 + 1]};
  float hold[2] = {h0[(u64)grow * HH_ + c0], h0[(u64)grow * HH_ + c0 + 1]};
  float* outp = out + (u64)grow * TT_ * HH_ + c0;   // + t*HH_ per step

  u32* dflag = flags + bg * 512;                     // 32 flags, stride 16 u32 (64B)
  const int fsl = (w * 8 + (l & 7)) * 16;            // this wave's 8 dep flags
  const u64 ldw = ((u64)(bb + lr) * HH_ + koff + lk * 8) >> 2;  // u64 idx, h load
  const u64 stw = ((u64)grow * HH_ + c0) >> 1;                  // u32 idx, h store

  for (int t = 0; t < TT_; ++t) {
    // xp prefetch (non-temporal; latency hides under the poll)
    union { u64 q; float f[2]; } xu;
    xu.q = __builtin_nontemporal_load((const u64*)(outp + (u64)t * HH_));

    if (t > 0) {
      // per-wave poll: only the 8 producers of this wave's k-slice
      const u32 need = (u32)t;
      while (true) {
        u32 v = __hip_atomic_load(dflag + fsl, __ATOMIC_RELAXED, __HIP_MEMORY_SCOPE_AGENT);
        if (__all((int)(v >= need))) break;
      }
    }

    // --- bulk pipelined h loads (relaxed agent u64 = LLC-direct), MFMA ---
    const u64* hB = (const u64*)hbuf + (u64)(t & 1) * (BB_ * HH_ / 4) + ldw;
    bf16x8 av[8];
#pragma unroll
    for (int kk = 0; kk < 8; ++kk) {
      union { u64 q[2]; bf16x8 v; } au;
      au.q[0] = __hip_atomic_load(hB + kk * 8,     __ATOMIC_RELAXED, __HIP_MEMORY_SCOPE_AGENT);
      au.q[1] = __hip_atomic_load(hB + kk * 8 + 1, __ATOMIC_RELAXED, __HIP_MEMORY_SCOPE_AGENT);
      av[kk] = au.v;
    }

    f32x4 acc[4] = {};
#pragma unroll
    for (int kk = 0; kk < 8; ++kk)
#pragma unroll
      for (int nt = 0; nt < 4; ++nt)
        asm("v_mfma_f32_16x16x32_bf16 %0, %1, %2, %0"
            : "+v"(acc[nt]) : "v"(av[kk]), "a"(wt[nt][kk]));
    // hazard fence: accs pass THROUGH the asm (r8-proven)
    asm volatile("s_nop 7\n\ts_nop 7\n\ts_nop 7"
                 : "+v"(acc[0]), "+v"(acc[1]), "+v"(acc[2]), "+v"(acc[3]));

    // --- K-partials to LDS: D[batch=lk*4+i][j=nt_tile*16+lr] ---
#pragma unroll
    for (int nt = 0; nt < 4; ++nt)
#pragma unroll
      for (int i = 0; i < 4; ++i)
        part[((w * 4 + nt) * 4 + i) * 65 + l] = acc[nt][i];
    __syncthreads();

    // --- combine + gates: thread owns (batch b, cols c0, c0+1) ---
    float hn[2];
#pragma unroll
    for (int q = 0; q < 2; ++q) {
      const int cl = jp * 2 + q;            // local col 0..31
      const int nt1 = cl >> 4, jl = cl & 15;
      const int lidx = (b >> 2) * 16 + jl, ridx = b & 3;
      float v1 = 0.f, v2 = 0.f;
#pragma unroll
      for (int ww = 0; ww < 4; ++ww) {
        v1 += part[((ww * 4 + nt1) * 4 + ridx) * 65 + lidx];
        v2 += part[((ww * 4 + 2 + nt1) * 4 + ridx) * 65 + lidx];
      }
      float xi = xu.f[q];
      float t1 = tanhfast(v1 + xi + bv1[q]);
      float t2 = tanhfast(v2 + xi + bv2[q]);
      hn[q] = t1 + hold[q] * (t2 - t1);  // (1-h)*v1 + h*v2
      hold[q] = hn[q];
    }

    // --- publish: u32 h-store, vmcnt(0), barrier, tid0 relaxed flag ---
    if (t < TT_ - 1) {
      u32 wd = (u32)bf16rne(hn[0]) | ((u32)bf16rne(hn[1]) << 16);
      __hip_atomic_store((u32*)hbuf + (u64)((t + 1) & 1) * (BB_ * HH_ / 2) + stw, wd,
                         __ATOMIC_RELAXED, __HIP_MEMORY_SCOPE_AGENT);
      asm volatile("s_waitcnt vmcnt(0)" ::: "memory");
      __syncthreads();  // all 256 threads' h-stores are in LLC; part[] WAR
      if (tid == 0)
        __hip_atomic_store(dflag + og * 16, (u32)(t + 1), __ATOMIC_RELAXED, __HIP_MEMORY_SCOPE_AGENT);
    }

    // --- trajectory / h_T stores, non-temporal, off the critical chain ---
    union { u64 q; float f[2]; } hu;
    hu.f[0] = hn[0]; hu.f[1] = hn[1];
    __builtin_nontemporal_store(hu.q, (u64*)(outp + (u64)t * HH_));
    if (t == TT_ - 1)
      __builtin_nontemporal_store(hu.q, (u64*)(out + (u64)BB_ * TT_ * HH_ + (u64)grow * HH_ + c0));
  }
}

// ---------------------------------------------------------------------------
extern "C" void kernel_launch(void* const* d_in, const int* in_sizes, int n_in,
                              void* d_out, int out_size, void* d_ws, size_t ws_size,
                              hipStream_t stream) {
  const float* x    = (const float*)d_in[0];
  const float* h0   = (const float*)d_in[1];
  const float* Wih  = (const float*)d_in[2];
  const float* bih  = (const float*)d_in[3];
  const float* Whh1 = (const float*)d_in[4];
  const float* bhh1 = (const float*)d_in[5];
  const float* Whh2 = (const float*)d_in[6];
  const float* bhh2 = (const float*)d_in[7];
  float* out = (float*)d_out;

  char* ws = (char*)d_ws;
  unsigned short* Wihb  = (unsigned short*)(ws + 0);          //  2 MiB
  unsigned short* Wcatb = (unsigned short*)(ws + 2097152);    //  4 MiB
  unsigned short* hbuf  = (unsigned short*)(ws + 6291456);    //  256 KiB (2 bf16 buffers)
  int*            cnt   = (int*)(ws + 6553600);               //  16 KiB (padded flags)
  unsigned short* xb    = (unsigned short*)(ws + 6569984);    //  64 MiB
  const bool fastx = ws_size >= 73678848ULL;

  hipLaunchKernelGGL(k_convert, dim3(2048), dim3(256), 0, stream,
                     x, h0, Wih, Whh1, Whh2, xb, Wihb, Wcatb, hbuf, cnt, (int)fastx);
  if (fastx)
    hipLaunchKernelGGL((k_gemm<true>), dim3(2048), dim3(256), 0, stream,
                       xb, (const float*)nullptr, Wihb, bih, out);
  else
    hipLaunchKernelGGL((k_gemm<false>), dim3(2048), dim3(256), 0, stream,
                       (const unsigned short*)nullptr, x, Wihb, bih, out);
  hipLaunchKernelGGL(k_scan, dim3(NSCAN_BLOCKS), dim3(256), 0, stream,
                     out, h0, bhh1, bhh2, Wcatb, hbuf, (u32*)cnt);
}